// Round 3
// baseline (521.438 us; speedup 1.0000x reference)
//
#include <hip/hip_runtime.h>
#include <math.h>

#define B_ 32
#define C_ 256
#define H_ 56
#define W_ 56
#define HW_ (H_*W_)        // 3136
#define Q_ (HW_/4)         // 784 float4 per (b,c) map
#define W4_ (W_/4)         // 14
#define R_ 16
#define K_ 7
#define KK_ (K_*K_)

__device__ __forceinline__ float sigmoidf_(float v) { return 1.0f / (1.0f + expf(-v)); }

// ============ Kernel 1: per-(b,c) mean/max pool + last-block MLP -> ca ============
// Grid: B_*C_ = 8192 blocks x 256 threads. Last finishing block computes the MLP.
__global__ void __launch_bounds__(256)
k_pool_mlp(const float* __restrict__ x, const float* __restrict__ w1,
           const float* __restrict__ w2, float* __restrict__ avg,
           float* __restrict__ mx, float* __restrict__ ca,
           unsigned* __restrict__ cnt) {
    const int bc = blockIdx.x;
    const float4* xp = (const float4*)(x + (size_t)bc * HW_);
    float s = 0.0f, m = -INFINITY;
    for (int i = threadIdx.x; i < Q_; i += 256) {
        float4 v = xp[i];
        s += v.x + v.y + v.z + v.w;
        m = fmaxf(m, fmaxf(fmaxf(v.x, v.y), fmaxf(v.z, v.w)));
    }
    #pragma unroll
    for (int off = 32; off > 0; off >>= 1) {
        s += __shfl_down(s, off, 64);
        m  = fmaxf(m, __shfl_down(m, off, 64));
    }
    __shared__ float ss[4], sm[4];
    __shared__ int lastFlag;
    const int wave = threadIdx.x >> 6;
    if ((threadIdx.x & 63) == 0) { ss[wave] = s; sm[wave] = m; }
    __syncthreads();
    if (threadIdx.x == 0) {
        float S = ss[0] + ss[1] + ss[2] + ss[3];
        float M = fmaxf(fmaxf(sm[0], sm[1]), fmaxf(sm[2], sm[3]));
        // agent-scope stores: visible device-wide once the release RMW below lands
        __hip_atomic_store(&avg[bc], S * (1.0f / HW_), __ATOMIC_RELAXED, __HIP_MEMORY_SCOPE_AGENT);
        __hip_atomic_store(&mx[bc],  M,                __ATOMIC_RELAXED, __HIP_MEMORY_SCOPE_AGENT);
        unsigned old = __hip_atomic_fetch_add(cnt, 1u, __ATOMIC_ACQ_REL, __HIP_MEMORY_SCOPE_AGENT);
        lastFlag = (old == (unsigned)(gridDim.x - 1)) ? 1 : 0;
    }
    __syncthreads();
    if (!lastFlag) return;

    // ---- last block: shared MLP for all 32 batches ----
    __shared__ float sv[8][2 * C_];   // 8 batches x (avg|mx)  = 16 KB
    __shared__ float sh[B_][R_];      // hidden = relu(ha)+relu(hm), 2 KB
    const int t = threadIdx.x;
    for (int g = 0; g < 4; ++g) {                 // 4 groups of 8 batches
        for (int i = t; i < 8 * C_; i += 256) {
            const int bb = i / C_, c = i % C_;
            const int b = g * 8 + bb;
            sv[bb][c]      = __hip_atomic_load(&avg[b * C_ + c], __ATOMIC_RELAXED, __HIP_MEMORY_SCOPE_AGENT);
            sv[bb][C_ + c] = __hip_atomic_load(&mx[b * C_ + c],  __ATOMIC_RELAXED, __HIP_MEMORY_SCOPE_AGENT);
        }
        __syncthreads();
        if (t < 8 * R_) {                          // 128 tasks: (bb, r)
            const int bb = t / R_, r = t % R_;
            float ha = 0.0f, hm = 0.0f;
            for (int c = 0; c < C_; ++c) {
                const float wv = w1[r * C_ + c];
                ha += wv * sv[bb][c];
                hm += wv * sv[bb][C_ + c];
            }
            sh[g * 8 + bb][r] = fmaxf(ha, 0.0f) + fmaxf(hm, 0.0f);
        }
        __syncthreads();
    }
    for (int k = t; k < B_ * C_; k += 256) {
        const int b = k / C_, c = k % C_;
        float acc = 0.0f;
        #pragma unroll
        for (int r = 0; r < R_; ++r) acc += w2[c * R_ + r] * sh[b][r];
        ca[k] = sigmoidf_(acc);
    }
}

// ============ Kernel 2: spatial pooled = {mean_c, max_c} of x*ca ============
// Block: 256 threads = 16 q-positions (float4) x 16 channel-groups. Grid (49, 32).
__global__ void __launch_bounds__(256)
k_spatial_pool(const float* __restrict__ x, const float* __restrict__ ca,
               float* __restrict__ pooled) {
    const int b  = blockIdx.y;
    const int q0 = blockIdx.x * 16;
    const int t  = threadIdx.x;
    const int tq = t & 15;
    const int tc = t >> 4;
    const int q  = q0 + tq;

    const float4* xp = (const float4*)(x + (size_t)b * C_ * HW_);
    const float* cab = ca + b * C_;

    float4 s = {0.f, 0.f, 0.f, 0.f};
    float4 m = {-INFINITY, -INFINITY, -INFINITY, -INFINITY};
    #pragma unroll 4
    for (int i = 0; i < 16; ++i) {
        const int c = tc * 16 + i;
        const float a = cab[c];
        float4 v = xp[(size_t)c * Q_ + q];
        v.x *= a; v.y *= a; v.z *= a; v.w *= a;
        s.x += v.x; s.y += v.y; s.z += v.z; s.w += v.w;
        m.x = fmaxf(m.x, v.x); m.y = fmaxf(m.y, v.y);
        m.z = fmaxf(m.z, v.z); m.w = fmaxf(m.w, v.w);
    }

    __shared__ float4 ls[256];
    __shared__ float4 lm[256];
    ls[t] = s; lm[t] = m;
    __syncthreads();
    #pragma unroll
    for (int st = 8; st >= 1; st >>= 1) {
        if (tc < st) {
            const int o = t + st * 16;
            float4 os = ls[o], om = lm[o];
            s.x += os.x; s.y += os.y; s.z += os.z; s.w += os.w;
            m.x = fmaxf(m.x, om.x); m.y = fmaxf(m.y, om.y);
            m.z = fmaxf(m.z, om.z); m.w = fmaxf(m.w, om.w);
            ls[t] = s; lm[t] = m;
        }
        __syncthreads();
    }
    if (tc == 0) {
        const float inv = 1.0f / C_;
        float4 sm4 = {s.x * inv, s.y * inv, s.z * inv, s.w * inv};
        ((float4*)(pooled + (size_t)b * 2 * HW_))[q]       = sm4;
        ((float4*)(pooled + (size_t)b * 2 * HW_ + HW_))[q] = m;
    }
}

// ============ Kernel 3: 7x7 conv + sigmoid (to LDS) + residual apply ============
// Grid (H_/2, B_) = (28, 32); each block: 2 rows, all 256 channels.
__global__ void __launch_bounds__(256)
k_conv_final(const float* __restrict__ x, const float* __restrict__ pooled,
             const float* __restrict__ wsp, const float* __restrict__ ca,
             float* __restrict__ out) {
    const int b  = blockIdx.y;
    const int h0 = blockIdx.x * 2;
    const int t  = threadIdx.x;
    __shared__ float wv[2 * KK_];
    __shared__ float s_sa[2 * W_];   // 112
    __shared__ float s_ca[C_];
    if (t < 2 * KK_) wv[t] = wsp[t];
    if (t < C_) s_ca[t] = ca[b * C_ + t];
    __syncthreads();
    if (t < 2 * W_) {
        const int row = t / W_;
        const int w   = t % W_;
        const int h   = h0 + row;
        const float* pa = pooled + (size_t)b * 2 * HW_;
        const float* pm = pa + HW_;
        float acc = 0.0f;
        #pragma unroll
        for (int ky = 0; ky < K_; ++ky) {
            const int y = h + ky - 3;
            if (y < 0 || y >= H_) continue;
            #pragma unroll
            for (int kx = 0; kx < K_; ++kx) {
                const int xx = w + kx - 3;
                if (xx < 0 || xx >= W_) continue;
                const int o = y * W_ + xx;
                acc += wv[ky * K_ + kx] * pa[o] + wv[KK_ + ky * K_ + kx] * pm[o];
            }
        }
        s_sa[t] = sigmoidf_(acc);
    }
    __syncthreads();
    // apply over (c, row, w4): C_*2*W4_ = 7168 float4s, 28 per thread
    const float4* xr   = (const float4*)(x + (size_t)b * C_ * HW_ + h0 * W_);
    float4*       outr = (float4*)((float*)out + (size_t)b * C_ * HW_ + h0 * W_);
    #pragma unroll 4
    for (int i = 0; i < 28; ++i) {
        const int j   = i * 256 + t;
        const int c   = j / 28;
        const int rem = j % 28;
        const int row = rem / W4_;
        const int w4  = rem % W4_;
        const size_t off4 = (size_t)c * (HW_ / 4) + row * W4_ + w4;
        const float4 v  = xr[off4];
        const float  a  = s_ca[c];
        const float4 sa4 = *(const float4*)&s_sa[row * W_ + w4 * 4];
        float4 o;
        o.x = v.x * (1.0f + a * sa4.x);
        o.y = v.y * (1.0f + a * sa4.y);
        o.z = v.z * (1.0f + a * sa4.z);
        o.w = v.w * (1.0f + a * sa4.w);
        outr[off4] = o;
    }
}

extern "C" void kernel_launch(void* const* d_in, const int* in_sizes, int n_in,
                              void* d_out, int out_size, void* d_ws, size_t ws_size,
                              hipStream_t stream) {
    const float* x   = (const float*)d_in[0];
    const float* w1  = (const float*)d_in[1];
    const float* w2  = (const float*)d_in[2];
    const float* wsp = (const float*)d_in[3];
    float* out = (float*)d_out;

    // workspace layout (floats)
    float* ws     = (float*)d_ws;
    float* avg    = ws;                             // B*C
    float* mx     = avg + B_ * C_;                  // B*C
    float* ca     = mx + B_ * C_;                   // B*C
    float* pooled = ca + B_ * C_;                   // B*2*HW
    unsigned* cnt = (unsigned*)(pooled + (size_t)B_ * 2 * HW_);

    // zero the completion counter (memset node is graph-capturable)
    hipMemsetAsync(cnt, 0, sizeof(unsigned), stream);

    // 1) channel pooling + MLP (last-block pattern)
    k_pool_mlp<<<B_ * C_, 256, 0, stream>>>(x, w1, w2, avg, mx, ca, cnt);
    // 2) spatial pooling of x*ca
    {
        dim3 g(Q_ / 16, B_);
        k_spatial_pool<<<g, 256, 0, stream>>>(x, ca, pooled);
    }
    // 3) 7x7 conv + sigmoid + residual finalize
    {
        dim3 g(H_ / 2, B_);
        k_conv_final<<<g, 256, 0, stream>>>(x, pooled, wsp, ca, out);
    }
}

// Round 4
// 236.222 us; speedup vs baseline: 2.2074x; 2.2074x over previous
//
#include <hip/hip_runtime.h>
#include <math.h>

#define B_ 32
#define C_ 256
#define H_ 56
#define W_ 56
#define HW_ (H_*W_)        // 3136
#define Q_ (HW_/4)         // 784 float4 per (b,c) map
#define W4_ (W_/4)         // 14
#define R_ 16
#define K_ 7
#define KK_ (K_*K_)

__device__ __forceinline__ float sigmoidf_(float v) { return 1.0f / (1.0f + expf(-v)); }

// ============ Kernel 1: per-(b,c) mean + max over HW ============
__global__ void __launch_bounds__(256)
k_pool_bc(const float* __restrict__ x,
          float* __restrict__ avg, float* __restrict__ mx) {
    const int bc = blockIdx.x;                      // 0 .. B*C-1
    const float4* xp = (const float4*)(x + (size_t)bc * HW_);
    float s = 0.0f, m = -INFINITY;
    for (int i = threadIdx.x; i < Q_; i += 256) {
        float4 v = xp[i];
        s += v.x + v.y + v.z + v.w;
        m = fmaxf(m, fmaxf(fmaxf(v.x, v.y), fmaxf(v.z, v.w)));
    }
    #pragma unroll
    for (int off = 32; off > 0; off >>= 1) {
        s += __shfl_down(s, off, 64);
        m  = fmaxf(m, __shfl_down(m, off, 64));
    }
    __shared__ float ss[4], sm[4];
    const int wave = threadIdx.x >> 6;
    if ((threadIdx.x & 63) == 0) { ss[wave] = s; sm[wave] = m; }
    __syncthreads();
    if (threadIdx.x == 0) {
        float S = ss[0] + ss[1] + ss[2] + ss[3];
        float M = fmaxf(fmaxf(sm[0], sm[1]), fmaxf(sm[2], sm[3]));
        avg[bc] = S * (1.0f / HW_);
        mx[bc]  = M;
    }
}

// ============ Kernel 2: shared MLP -> channel attention ============
__global__ void __launch_bounds__(256)
k_mlp_ca(const float* __restrict__ avg, const float* __restrict__ mx,
         const float* __restrict__ w1, const float* __restrict__ w2,
         float* __restrict__ ca) {
    const int b = blockIdx.x;
    __shared__ float sa_[C_], sm_[C_], h_[R_];
    const int t = threadIdx.x;                      // blockDim.x == C_
    sa_[t] = avg[b * C_ + t];
    sm_[t] = mx[b * C_ + t];
    __syncthreads();
    if (t < R_) {
        float ha = 0.0f, hm = 0.0f;
        for (int c = 0; c < C_; ++c) {
            const float wv = w1[t * C_ + c];
            ha += wv * sa_[c];
            hm += wv * sm_[c];
        }
        h_[t] = fmaxf(ha, 0.0f) + fmaxf(hm, 0.0f);
    }
    __syncthreads();
    float acc = 0.0f;
    #pragma unroll
    for (int r = 0; r < R_; ++r) acc += w2[t * R_ + r] * h_[r];
    ca[b * C_ + t] = sigmoidf_(acc);
}

// ============ Kernel 3: spatial pooled = {mean_c, max_c} of x*ca ============
// Block: 256 threads = 16 q-positions (float4) x 16 channel-groups. Grid (49, 32).
__global__ void __launch_bounds__(256)
k_spatial_pool(const float* __restrict__ x, const float* __restrict__ ca,
               float* __restrict__ pooled) {
    const int b  = blockIdx.y;
    const int q0 = blockIdx.x * 16;
    const int t  = threadIdx.x;
    const int tq = t & 15;
    const int tc = t >> 4;
    const int q  = q0 + tq;

    const float4* xp = (const float4*)(x + (size_t)b * C_ * HW_);
    const float* cab = ca + b * C_;

    float4 s = {0.f, 0.f, 0.f, 0.f};
    float4 m = {-INFINITY, -INFINITY, -INFINITY, -INFINITY};
    #pragma unroll 4
    for (int i = 0; i < 16; ++i) {
        const int c = tc * 16 + i;
        const float a = cab[c];
        float4 v = xp[(size_t)c * Q_ + q];
        v.x *= a; v.y *= a; v.z *= a; v.w *= a;
        s.x += v.x; s.y += v.y; s.z += v.z; s.w += v.w;
        m.x = fmaxf(m.x, v.x); m.y = fmaxf(m.y, v.y);
        m.z = fmaxf(m.z, v.z); m.w = fmaxf(m.w, v.w);
    }

    __shared__ float4 ls[256];
    __shared__ float4 lm[256];
    ls[t] = s; lm[t] = m;
    __syncthreads();
    #pragma unroll
    for (int st = 8; st >= 1; st >>= 1) {
        if (tc < st) {
            const int o = t + st * 16;
            float4 os = ls[o], om = lm[o];
            s.x += os.x; s.y += os.y; s.z += os.z; s.w += os.w;
            m.x = fmaxf(m.x, om.x); m.y = fmaxf(m.y, om.y);
            m.z = fmaxf(m.z, om.z); m.w = fmaxf(m.w, om.w);
            ls[t] = s; lm[t] = m;
        }
        __syncthreads();
    }
    if (tc == 0) {
        const float inv = 1.0f / C_;
        float4 sm4 = {s.x * inv, s.y * inv, s.z * inv, s.w * inv};
        ((float4*)(pooled + (size_t)b * 2 * HW_))[q]       = sm4;
        ((float4*)(pooled + (size_t)b * 2 * HW_ + HW_))[q] = m;
    }
}

// ============ Kernel 4: 7x7 conv + sigmoid (to LDS) + residual apply ============
// Grid (H_/2, B_) = (28, 32); each block: 2 rows, all 256 channels.
__global__ void __launch_bounds__(256)
k_conv_final(const float* __restrict__ x, const float* __restrict__ pooled,
             const float* __restrict__ wsp, const float* __restrict__ ca,
             float* __restrict__ out) {
    const int b  = blockIdx.y;
    const int h0 = blockIdx.x * 2;
    const int t  = threadIdx.x;
    __shared__ float wv[2 * KK_];
    __shared__ float s_sa[2 * W_];   // 112
    __shared__ float s_ca[C_];
    if (t < 2 * KK_) wv[t] = wsp[t];
    if (t < C_) s_ca[t] = ca[b * C_ + t];
    __syncthreads();
    if (t < 2 * W_) {
        const int row = t / W_;
        const int w   = t % W_;
        const int h   = h0 + row;
        const float* pa = pooled + (size_t)b * 2 * HW_;
        const float* pm = pa + HW_;
        float acc = 0.0f;
        #pragma unroll
        for (int ky = 0; ky < K_; ++ky) {
            const int y = h + ky - 3;
            if (y < 0 || y >= H_) continue;
            #pragma unroll
            for (int kx = 0; kx < K_; ++kx) {
                const int xx = w + kx - 3;
                if (xx < 0 || xx >= W_) continue;
                const int o = y * W_ + xx;
                acc += wv[ky * K_ + kx] * pa[o] + wv[KK_ + ky * K_ + kx] * pm[o];
            }
        }
        s_sa[t] = sigmoidf_(acc);
    }
    __syncthreads();
    // apply over (c, row, w4): C_*2*W4_ = 7168 float4s, 28 per thread
    const float4* xr   = (const float4*)(x + (size_t)b * C_ * HW_ + h0 * W_);
    float4*       outr = (float4*)((float*)out + (size_t)b * C_ * HW_ + h0 * W_);
    int c   = t / 28;            // 28 slots per channel-pair of rows
    int rem = t % 28;
    #pragma unroll 4
    for (int i = 0; i < 28; ++i) {
        const int row = rem / W4_;
        const int w4  = rem % W4_;
        const size_t off4 = (size_t)c * (HW_ / 4) + row * W4_ + w4;
        const float4 v  = xr[off4];
        const float  a  = s_ca[c];
        const float4 sa4 = *(const float4*)&s_sa[row * W_ + w4 * 4];
        float4 o;
        o.x = v.x * (1.0f + a * sa4.x);
        o.y = v.y * (1.0f + a * sa4.y);
        o.z = v.z * (1.0f + a * sa4.z);
        o.w = v.w * (1.0f + a * sa4.w);
        outr[off4] = o;
        // advance by 256 slots: 256 = 9*28 + 4
        c += 9; rem += 4;
        if (rem >= 28) { rem -= 28; c += 1; }
    }
}

extern "C" void kernel_launch(void* const* d_in, const int* in_sizes, int n_in,
                              void* d_out, int out_size, void* d_ws, size_t ws_size,
                              hipStream_t stream) {
    const float* x   = (const float*)d_in[0];
    const float* w1  = (const float*)d_in[1];
    const float* w2  = (const float*)d_in[2];
    const float* wsp = (const float*)d_in[3];
    float* out = (float*)d_out;

    // workspace layout (floats)
    float* ws     = (float*)d_ws;
    float* avg    = ws;                             // B*C
    float* mx     = avg + B_ * C_;                  // B*C
    float* ca     = mx + B_ * C_;                   // B*C
    float* pooled = ca + B_ * C_;                   // B*2*HW

    // 1) channel-wise pooling
    k_pool_bc<<<B_ * C_, 256, 0, stream>>>(x, avg, mx);
    // 2) MLP -> channel attention
    k_mlp_ca<<<B_, C_, 0, stream>>>(avg, mx, w1, w2, ca);
    // 3) spatial pooling of x*ca
    {
        dim3 g(Q_ / 16, B_);
        k_spatial_pool<<<g, 256, 0, stream>>>(x, ca, pooled);
    }
    // 4) 7x7 conv + sigmoid + residual finalize
    {
        dim3 g(H_ / 2, B_);
        k_conv_final<<<g, 256, 0, stream>>>(x, pooled, wsp, ca, out);
    }
}